// Round 9
// baseline (6240.027 us; speedup 1.0000x reference)
//
#include <hip/hip_runtime.h>
#include <stdint.h>

// GTCN2 Round 14:
//  - R11-R13 established: gather floor ~200us/hop (740MB @ ~3.8TB/s); the
//    ~60us/hop gap is the GEMM tail serialized by block-phase lockstep.
//  - R14: wave-independent fused hop. Wave = work unit: grabs a 16-row chunk
//    from a global atomic counter, gathers into its PRIVATE 8KB LDS region,
//    hoists A-frags to regs, GEMMs 16x256 (4 passes x 64 cols, B coalesced
//    from W3f), epilogue, next chunk. ZERO barriers; waves desync so MFMA
//    rides under other waves' gathers. 32KB LDS/block -> 5 blocks/CU,
//    launch_bounds(256,4) caps VGPR at 128 (est ~90). 6250 chunks, dynamic
//    stealing -> no grid tail (100000 = 6250*16 exactly).
//  - CSR build / GEMM1 / out-GEMM unchanged from R13.

typedef unsigned short bf16_t;
typedef __attribute__((ext_vector_type(8))) short bf16x8;
typedef __attribute__((ext_vector_type(8))) unsigned short u16x8;
typedef __attribute__((ext_vector_type(4))) float f32x4;

__device__ __forceinline__ float bf2f(bf16_t u) {
    union { unsigned int i; float f; } v; v.i = ((unsigned int)u) << 16; return v.f;
}
__device__ __forceinline__ bf16_t f2bf(float f) {
    union { float f; unsigned int i; } v; v.f = f;
    unsigned int x = v.i;
    unsigned int r = (x + 0x7fffu + ((x >> 16) & 1u)) >> 16;  // RNE
    return (bf16_t)r;
}

__global__ void zero_i32(int* __restrict__ p, int n) {
    int i = blockIdx.x * blockDim.x + threadIdx.x;
    if (i < n) p[i] = 0;
}

// W: KxN fp32 -> Wt: NxK bf16 (so GEMM B-staging == A-staging pattern).
__global__ void transpose_w(const float* __restrict__ W, bf16_t* __restrict__ Wt,
                            int K, int N) {
    int i = blockIdx.x * blockDim.x + threadIdx.x;
    if (i < K * N) {
        int k = i / N, n = i % N;
        Wt[(size_t)n * K + k] = f2bf(W[i]);
    }
}

// W3 (256x256 fp32, W3[k][n]) -> fragment-ordered bf16 for the fused GEMM.
// frag f = ((g*8+ks)*4+ns)*64+lane, elem j (k-consecutive):
//   W3f[f*8+j] = bf16( W3[(ks*32+(lane>>4)*8+j)*256 + (g*64+ns*16+(lane&15))] )
__global__ void make_w3frag(const float* __restrict__ W3, bf16_t* __restrict__ W3f) {
    int t = blockIdx.x * blockDim.x + threadIdx.x;   // 0..65535
    int j = t & 7;
    int f = t >> 3;
    int lane = f & 63;
    int ns = (f >> 6) & 3;
    int ks = (f >> 8) & 7;
    int g = f >> 11;
    int k = ks * 32 + ((lane >> 4) << 3) + j;
    int n = g * 64 + ns * 16 + (lane & 15);
    W3f[t] = f2bf(W3[k * 256 + n]);
}

#define BIN_CHUNK 8192
#define NBMAX 392

// Bucket-level histogram: LDS-aggregated, <=NB global atomics per block.
__global__ __launch_bounds__(256)
void bin_count(const int* __restrict__ er, int* __restrict__ bcnt, int E, int N,
               int NB) {
    __shared__ int cnt[NBMAX];
    int tid = threadIdx.x;
    for (int b = tid; b < NB; b += 256) cnt[b] = 0;
    __syncthreads();
    int e0 = blockIdx.x * BIN_CHUNK;
    int n = min(BIN_CHUNK, E - e0);
    for (int i = tid; i < n; i += 256) {
        unsigned r = (unsigned)er[e0 + i];
        if (r < (unsigned)N) atomicAdd(&cnt[r >> 8], 1);
    }
    __syncthreads();
    for (int b = tid; b < NB; b += 256) {
        int c = cnt[b];
        if (c) atomicAdd(&bcnt[b], c);
    }
}

// Exclusive scan over NB (<512) bucket counts -> bucket_base[NB+1], bcur copy.
__global__ __launch_bounds__(512)
void scan_buckets(const int* __restrict__ bcnt, int* __restrict__ bucket_base,
                  int* __restrict__ bcur, int NB) {
    __shared__ int s[512];
    int t = threadIdx.x;
    int v = (t < NB) ? bcnt[t] : 0;
    s[t] = v;
    __syncthreads();
    for (int off = 1; off < 512; off <<= 1) {
        int u = (t >= off) ? s[t - off] : 0;
        __syncthreads();
        s[t] += u;
        __syncthreads();
    }
    if (t < NB) {
        int excl = s[t] - v;
        bucket_base[t] = excl;
        bcur[t] = excl;
        if (t == NB - 1) bucket_base[NB] = s[t];
    }
}

// Pass 1: bin edges into 256-row buckets. Packed entry: .x = r_local<<17 | c
// (c < 2^17), .y = float bits of val.
__global__ __launch_bounds__(256)
void bin_edges(const int* __restrict__ er, const int* __restrict__ ec,
               const float* __restrict__ ev, int* __restrict__ bcur,
               int2* __restrict__ binned, int E, int N, int NB) {
    __shared__ int cnt[NBMAX];
    __shared__ int resv[NBMAX];
    int tid = threadIdx.x;
    int e0 = blockIdx.x * BIN_CHUNK;
    int n = min(BIN_CHUNK, E - e0);
    for (int b = tid; b < NB; b += 256) cnt[b] = 0;
    __syncthreads();
    for (int i = tid; i < n; i += 256) {
        unsigned r = (unsigned)er[e0 + i];
        if (r < (unsigned)N) atomicAdd(&cnt[r >> 8], 1);
    }
    __syncthreads();
    for (int b = tid; b < NB; b += 256) {
        int c = cnt[b];
        resv[b] = c ? atomicAdd(&bcur[b], c) : 0;
        cnt[b] = 0;  // reuse as local cursor
    }
    __syncthreads();
    for (int i = tid; i < n; i += 256) {
        unsigned r = (unsigned)er[e0 + i];
        if (r < (unsigned)N) {
            unsigned c = (unsigned)ec[e0 + i];
            float v = ev[e0 + i];
            if (c >= (unsigned)N) { c = 0; v = 0.f; }  // sanitize, keep slot
            int b = (int)(r >> 8);
            int p = resv[b] + atomicAdd(&cnt[b], 1);
            binned[p] = make_int2((int)(((r & 255u) << 17) | c), __float_as_int(v));
        }
    }
}

// Pass 2: sort one bucket into exact CSR row order (in place via LDS staging)
// and emit row_ptr for its 256 rows from the in-LDS scan.
#define BCAP 9216
__global__ __launch_bounds__(256)
void bucket_sort(const int* __restrict__ bucket_base, int2* __restrict__ csr,
                 int* __restrict__ row_ptr, int N, int NB) {
    __shared__ int2 ent[BCAP];
    __shared__ int cnt[256];
    __shared__ int base[256];
    __shared__ int lcur[256];
    int b = blockIdx.x;
    int tid = threadIdx.x;
    int r0 = b << 8;
    int e0 = bucket_base[b];
    int e1 = bucket_base[b + 1];
    int n = e1 - e0;
    cnt[tid] = 0;
    __syncthreads();
    for (int i = tid; i < n; i += 256) {
        int2 p = csr[e0 + i];
        if (i < BCAP) ent[i] = p;
        atomicAdd(&cnt[((unsigned)p.x >> 17) & 255u], 1);
    }
    __syncthreads();
    int v0 = cnt[tid];
    for (int off = 1; off < 256; off <<= 1) {
        int u = (tid >= off) ? cnt[tid - off] : 0;
        __syncthreads();
        cnt[tid] += u;
        __syncthreads();
    }
    base[tid] = cnt[tid] - v0;  // exclusive scan
    lcur[tid] = 0;
    if (r0 + tid < N) row_ptr[r0 + tid] = e0 + cnt[tid] - v0;
    if (b == NB - 1 && tid == 255) row_ptr[N] = e1;
    __syncthreads();
    for (int i = tid; i < n; i += 256) {
        int2 p = (i < BCAP) ? ent[i] : csr[e0 + i];  // tail branch unreachable
        int rl = (int)(((unsigned)p.x >> 17) & 255u);
        int d = base[rl] + atomicAdd(&lcur[rl], 1);
        csr[e0 + d] = make_int2(p.x & 0x1FFFF, p.y);
    }
}

__device__ __forceinline__ void fma8(float* acc, float v, u16x8 hv) {
    #pragma unroll
    for (int k = 0; k < 8; ++k)
        acc[k] = fmaf(v, bf2f((bf16_t)hv[k]), acc[k]);
}

// Wave-independent fused hop. Each wave: pull 16-row chunk from ctr, gather
// rows into its private 8KB LDS region (swizzled), hoist A-frags to regs,
// GEMM 16x256 in 4 column passes (B coalesced from W3f), epilogue, repeat.
// NO block-wide barriers anywhere: waves desync, MFMA overlaps gathers.
__global__ __launch_bounds__(256, 4)
void fused_hop(const int* __restrict__ row_ptr, const int2* __restrict__ csr,
               const bf16_t* __restrict__ hin, const bf16_t* __restrict__ x0,
               const float* __restrict__ A2, const bf16_t* __restrict__ W3f,
               const float* __restrict__ bias, bf16_t* __restrict__ hout,
               int* __restrict__ ctr, int M) {
    __shared__ bf16_t s_tile[4 * 16 * 256];   // 8 KB per wave, 32 KB total
    const int w = threadIdx.x >> 6, lane = threadIdx.x & 63;
    char* stb = (char*)s_tile + (w << 13);    // this wave's 16x512B region
    const int half = lane >> 5, l32 = lane & 31, fo = l32 << 3;
    const int q = lane >> 4, l16 = lane & 15;
    const int nchunk = (M + 15) >> 4;

    for (;;) {
        int chunk;
        if (lane == 0) chunk = atomicAdd(ctr, 1);
        chunk = __shfl(chunk, 0, 64);
        if (chunk >= nchunk) break;
        const int bm = chunk << 4;

        // ---- gather 16 rows into stb ----
        for (int rr = 0; rr < 16; ++rr) {
            int row = bm + rr;
            float acc[8];
            #pragma unroll
            for (int k = 0; k < 8; ++k) acc[k] = 0.f;
            if (row < M) {
                if (half == 0) {
                    float a2 = A2[row];
                    u16x8 xv = *(const u16x8*)&x0[(row << 8) + fo];
                    #pragma unroll
                    for (int k = 0; k < 8; ++k) acc[k] = a2 * bf2f((bf16_t)xv[k]);
                }
                int e = row_ptr[row], e1 = row_ptr[row + 1];
                int nb = (e1 - e) >> 3;
                int2 q0, q1, q2, q3;
                if (nb > 0) {
                    int eb = e + half;
                    q0 = csr[eb]; q1 = csr[eb + 2]; q2 = csr[eb + 4]; q3 = csr[eb + 6];
                }
                for (int b = 0; b < nb; ++b) {
                    int2 p0 = q0, p1 = q1, p2 = q2, p3 = q3;
                    if (b + 1 < nb) {
                        int eb = e + 8 + half;
                        q0 = csr[eb]; q1 = csr[eb + 2]; q2 = csr[eb + 4]; q3 = csr[eb + 6];
                    }
                    u16x8 h0 = *(const u16x8*)&hin[(p0.x << 8) + fo];
                    u16x8 h1 = *(const u16x8*)&hin[(p1.x << 8) + fo];
                    u16x8 h2 = *(const u16x8*)&hin[(p2.x << 8) + fo];
                    u16x8 h3 = *(const u16x8*)&hin[(p3.x << 8) + fo];
                    fma8(acc, __int_as_float(p0.y), h0);
                    fma8(acc, __int_as_float(p1.y), h1);
                    fma8(acc, __int_as_float(p2.y), h2);
                    fma8(acc, __int_as_float(p3.y), h3);
                    e += 8;
                }
                for (; e + 2 <= e1; e += 2) {
                    int2 p = csr[e + half];
                    u16x8 hv = *(const u16x8*)&hin[(p.x << 8) + fo];
                    fma8(acc, __int_as_float(p.y), hv);
                }
                if (e < e1 && half == 0) {
                    int2 p = csr[e];
                    u16x8 hv = *(const u16x8*)&hin[(p.x << 8) + fo];
                    fma8(acc, __int_as_float(p.y), hv);
                }
                #pragma unroll
                for (int k = 0; k < 8; ++k) acc[k] += __shfl_xor(acc[k], 32, 64);
            }
            if (half == 0) {
                u16x8 o;
                #pragma unroll
                for (int k = 0; k < 8; ++k) o[k] = f2bf(acc[k]);
                *(u16x8*)(stb + rr * 512 + ((fo << 1) ^ ((rr & 7) << 4))) = o;
            }
        }
        // same-wave ds_write -> ds_read: compiler inserts lgkmcnt waits.

        // ---- hoist A-frags (16 rows x K=256) into 8 regs-of-8 ----
        bf16x8 afr[8];
        #pragma unroll
        for (int ks = 0; ks < 8; ++ks)
            afr[ks] = *(const bf16x8*)(stb + l16 * 512 +
                       ((((ks << 5) + q * 8) << 1) ^ ((l16 & 7) << 4)));

        // ---- GEMM 16x256 in 4 column passes + fused epilogue ----
        #pragma unroll
        for (int g = 0; g < 4; ++g) {
            const bf16x8* bf = (const bf16x8*)W3f + ((size_t)g << 11);
            f32x4 acc2[4] = {};
            #pragma unroll
            for (int ks = 0; ks < 8; ++ks) {
                bf16x8 bfr[4];
                #pragma unroll
                for (int ns = 0; ns < 4; ++ns)
                    bfr[ns] = bf[(ks * 4 + ns) * 64 + lane];  // base + 16*lane
                #pragma unroll
                for (int ns = 0; ns < 4; ++ns)
                    acc2[ns] = __builtin_amdgcn_mfma_f32_16x16x32_bf16(
                        afr[ks], bfr[ns], acc2[ns], 0, 0, 0);
            }
            #pragma unroll
            for (int ns = 0; ns < 4; ++ns) {
                #pragma unroll
                for (int r = 0; r < 4; ++r) {
                    int lrow = q * 4 + r;
                    int grow = bm + lrow;
                    if (grow < M) {
                        int col = g * 64 + ns * 16 + l16;
                        float v = acc2[ns][r] + bias[col];
                        v += bf2f(*(const bf16_t*)(stb + lrow * 512 +
                                  ((col << 1) ^ ((lrow & 7) << 4))));
                        v = fmaxf(v, 0.f);
                        hout[(size_t)grow * 256 + col] = f2bf(v);
                    }
                }
            }
        }
    }
}

// MFMA GEMM: C[M,Nfull] = epi(A[M,K] @ Bt[Nfull,K]^T). 4 waves, wave 64x64.
template <int WM, int WN, bool AF32, bool RELU, typename CT>
__global__ __launch_bounds__(256)
void mfma_gemm(const void* __restrict__ Av, const bf16_t* __restrict__ Bt,
               const float* __restrict__ bias, CT* __restrict__ C,
               int M, int K, int Nfull) {
    constexpr int TM = WM * 64;
    constexpr int TN = WN * 64;
    __shared__ bf16_t As[TM * 32];
    __shared__ bf16_t Bs[TN * 32];
    const int tid = threadIdx.x;
    const int w = tid >> 6, lane = tid & 63;
    const int q = lane >> 4, l16 = lane & 15;
    const int bm = blockIdx.x * TM;
    const int bn = blockIdx.y * TN;
    const int wm = (w % WM) * 64;
    const int wn = (w / WM) * 64;

    f32x4 acc[4][4] = {};

    for (int k0 = 0; k0 < K; k0 += 32) {
        // ---- stage A tile [TM][32] ----
        if constexpr (AF32) {
            constexpr int TPR = 256 / TM;      // threads per row
            constexpr int EPT = TM / 8;        // fp32 elems per thread
            const float* A = (const float*)Av;
            int row = tid / TPR;
            int gr = min(bm + row, M - 1);
            int off = (tid % TPR) * EPT;
            const float* src = A + (size_t)gr * K + k0 + off;
            bf16_t* dst = As + row * 32 + off;
            #pragma unroll
            for (int g = 0; g < EPT / 4; ++g) {
                float4 v = *(const float4*)(src + 4 * g);
                ushort4 u;
                u.x = f2bf(v.x); u.y = f2bf(v.y); u.z = f2bf(v.z); u.w = f2bf(v.w);
                *(ushort4*)(dst + 4 * g) = u;
            }
        } else {
            const bf16_t* A = (const bf16_t*)Av;
            #pragma unroll
            for (int r = 0; r < TM / 64; ++r) {
                int rowbase = r * 64 + w * 16;           // wave-uniform
                int row = rowbase + (lane >> 2);
                int gr = min(bm + row, M - 1);           // clamp tail rows
                const bf16_t* gp = A + (size_t)gr * K + k0 + (lane & 3) * 8;
                bf16_t* lp = As + rowbase * 32 + lane * 8;
                __builtin_amdgcn_global_load_lds(
                    (const __attribute__((address_space(1))) unsigned int*)gp,
                    (__attribute__((address_space(3))) unsigned int*)lp, 16, 0, 0);
            }
        }
        // ---- stage B tile [TN][32] from Bt (NxK row-major) ----
        #pragma unroll
        for (int r = 0; r < TN / 64; ++r) {
            int rowbase = r * 64 + w * 16;
            int row = rowbase + (lane >> 2);
            const bf16_t* gp = Bt + (size_t)(bn + row) * K + k0 + (lane & 3) * 8;
            bf16_t* lp = Bs + rowbase * 32 + lane * 8;
            __builtin_amdgcn_global_load_lds(
                (const __attribute__((address_space(1))) unsigned int*)gp,
                (__attribute__((address_space(3))) unsigned int*)lp, 16, 0, 0);
        }
        __syncthreads();

        bf16x8 afr[4], bfr[4];
        #pragma unroll
        for (int ms = 0; ms < 4; ++ms)
            afr[ms] = *(const bf16x8*)&As[(wm + ms * 16 + l16) * 32 + q * 8];
        #pragma unroll
        for (int ns = 0; ns < 4; ++ns)
            bfr[ns] = *(const bf16x8*)&Bs[(wn + ns * 16 + l16) * 32 + q * 8];
        #pragma unroll
        for (int ms = 0; ms < 4; ++ms)
            #pragma unroll
            for (int ns = 0; ns < 4; ++ns)
                acc[ms][ns] = __builtin_amdgcn_mfma_f32_16x16x32_bf16(
                    afr[ms], bfr[ns], acc[ms][ns], 0, 0, 0);
        __syncthreads();
    }

    // ---- epilogue ----
    #pragma unroll
    for (int ms = 0; ms < 4; ++ms) {
        #pragma unroll
        for (int r = 0; r < 4; ++r) {
            int row = bm + wm + ms * 16 + q * 4 + r;
            if (row < M) {
                #pragma unroll
                for (int ns = 0; ns < 4; ++ns) {
                    int col = bn + wn + ns * 16 + l16;
                    float v = acc[ms][ns][r] + bias[col];
                    if constexpr (RELU) v = fmaxf(v, 0.f);
                    if constexpr (sizeof(CT) == 2) C[(size_t)row * Nfull + col] = (CT)f2bf(v);
                    else                           C[(size_t)row * Nfull + col] = (CT)v;
                }
            }
        }
    }
}

extern "C" void kernel_launch(void* const* d_in, const int* in_sizes, int n_in,
                              void* d_out, int out_size, void* d_ws, size_t ws_size,
                              hipStream_t stream) {
    const float* x   = (const float*)d_in[0];
    const int* erow  = (const int*)d_in[1];
    const int* ecol  = (const int*)d_in[2];
    const float* ev  = (const float*)d_in[3];
    const float* A2  = (const float*)d_in[4];
    const float* W1  = (const float*)d_in[5];
    const float* b1  = (const float*)d_in[6];
    const float* W3  = (const float*)d_in[7];
    const float* b3  = (const float*)d_in[8];
    const float* W2  = (const float*)d_in[9];
    const float* b2  = (const float*)d_in[10];
    float* out = (float*)d_out;

    const int N   = in_sizes[4];        // 100000 nodes
    const int E   = in_sizes[1];        // 3200000 edges
    const int NIN = in_sizes[0] / N;    // 512
    const int NH  = in_sizes[6];        // 256
    const int NO  = in_sizes[10];       // 64
    if (NH != 256 || NIN != 512 || NO != 64) return;  // layout hard-coded
    const int NB = (N + 255) >> 8;      // 391 buckets
    if (NB > NBMAX) return;

    char* ws = (char*)d_ws;
    size_t off = 0;
    auto alloc = [&](size_t bytes) -> void* {
        void* p = ws + off;
        off += (bytes + 255) & ~(size_t)255;
        return p;
    };
    bf16_t* x0     = (bf16_t*)alloc((size_t)N * NH * 2);
    bf16_t* hA     = (bf16_t*)alloc((size_t)N * NH * 2);
    bf16_t* hB     = (bf16_t*)alloc((size_t)N * NH * 2);
    int*   row_ptr = (int*)alloc((size_t)(N + 1) * 4);
    int*   bcnt    = (int*)alloc((size_t)NB * 4);
    int*   bbase   = (int*)alloc((size_t)(NB + 1) * 4);
    int*   bcur    = (int*)alloc((size_t)NB * 4);
    int*   hopctr  = (int*)alloc((size_t)16 * 4);
    int2*  csr     = (int2*)alloc((size_t)E * 8);
    bf16_t* W1t    = (bf16_t*)alloc((size_t)NIN * NH * 2);  // [256][512]
    bf16_t* W3f    = (bf16_t*)alloc((size_t)NH * NH * 2);   // fragment-ordered
    bf16_t* W2t    = (bf16_t*)alloc((size_t)NH * NO * 2);   // [64][256]
    if (off > ws_size) return;  // visible absmax failure, not an OOB crash

    // --- build CSR (two-pass bucketed, bucket-level counting) ---
    zero_i32<<<1, 512, 0, stream>>>(bcnt, NB);
    zero_i32<<<1, 32, 0, stream>>>(hopctr, 16);
    bin_count<<<(E + BIN_CHUNK - 1) / BIN_CHUNK, 256, 0, stream>>>(
        erow, bcnt, E, N, NB);
    scan_buckets<<<1, 512, 0, stream>>>(bcnt, bbase, bcur, NB);
    bin_edges<<<(E + BIN_CHUNK - 1) / BIN_CHUNK, 256, 0, stream>>>(
        erow, ecol, ev, bcur, csr, E, N, NB);
    bucket_sort<<<NB, 256, 0, stream>>>(bbase, csr, row_ptr, N, NB);
    transpose_w<<<(NIN * NH + 255) / 256, 256, 0, stream>>>(W1, W1t, NIN, NH);
    make_w3frag<<<(NH * NH + 255) / 256, 256, 0, stream>>>(W3, W3f);
    transpose_w<<<(NH * NO + 255) / 256, 256, 0, stream>>>(W2, W2t, NH, NO);

    // --- x0 = relu(x @ W1 + b1): fp32 A, 64x256 tile (A read once) ---
    dim3 g1((N + 63) / 64, 1);
    mfma_gemm<1, 4, true, true, bf16_t><<<g1, 256, 0, stream>>>(
        x, W1t, b1, x0, N, NIN, NH);

    // --- 10 fused hops (persistent-ish waves, dynamic 16-row chunks) ---
    const bf16_t* hin = x0;
    bf16_t* hout = hA;
    for (int hop = 0; hop < 10; ++hop) {
        fused_hop<<<1280, 256, 0, stream>>>(
            row_ptr, csr, hin, x0, A2, W3f, b3, hout, hopctr + hop, N);
        hin = hout;
        hout = (hout == hA) ? hB : hA;
    }

    // --- out = h @ W2 + b2: 256x64 tile (N=64) ---
    dim3 g2((N + 255) / 256, 1);
    mfma_gemm<4, 1, false, false, float><<<g2, 256, 0, stream>>>(
        (const void*)hin, W2t, b2, out, N, NH, NO);
}

// Round 10
// 2987.751 us; speedup vs baseline: 2.0885x; 2.0885x over previous
//
#include <hip/hip_runtime.h>
#include <stdint.h>

// GTCN2 Round 15:
//  - R14 (wave-independent chunks) regressed 2.3x: dynamic stealing destroyed
//    L2 locality (FETCH 814MB->1.03GB, WRITE 101->451MB). Reverted to R13.
//  - R15 attacks gather OVER-FETCH (814MB vs ~130MB floor): CSR now sorted
//    within-row by ascending column (bucket_sort pass A by c>>9, pass B by
//    row), and fused_hop phase 1 interleaves 4 rows per wave (round-robin
//    8-edge batches) so all ~20K resident rows sweep the column space in
//    tandem -> each h line fetched once per generation, hit ~6x. Also 4x
//    more gathers in flight per wave.
//  - Phase 2 GEMM / CSR build / GEMM1 / out-GEMM unchanged from R13.

typedef unsigned short bf16_t;
typedef __attribute__((ext_vector_type(8))) short bf16x8;
typedef __attribute__((ext_vector_type(8))) unsigned short u16x8;
typedef __attribute__((ext_vector_type(4))) float f32x4;

__device__ __forceinline__ float bf2f(bf16_t u) {
    union { unsigned int i; float f; } v; v.i = ((unsigned int)u) << 16; return v.f;
}
__device__ __forceinline__ bf16_t f2bf(float f) {
    union { float f; unsigned int i; } v; v.f = f;
    unsigned int x = v.i;
    unsigned int r = (x + 0x7fffu + ((x >> 16) & 1u)) >> 16;  // RNE
    return (bf16_t)r;
}

__global__ void zero_i32(int* __restrict__ p, int n) {
    int i = blockIdx.x * blockDim.x + threadIdx.x;
    if (i < n) p[i] = 0;
}

// W: KxN fp32 -> Wt: NxK bf16 (so GEMM B-staging == A-staging pattern).
__global__ void transpose_w(const float* __restrict__ W, bf16_t* __restrict__ Wt,
                            int K, int N) {
    int i = blockIdx.x * blockDim.x + threadIdx.x;
    if (i < K * N) {
        int k = i / N, n = i % N;
        Wt[(size_t)n * K + k] = f2bf(W[i]);
    }
}

// W3 (256x256 fp32, W3[k][n]) -> fragment-ordered bf16 for the fused GEMM.
// frag f = ((g*8+ks)*4+ns)*64+lane, elem j (k-consecutive):
//   W3f[f*8+j] = bf16( W3[(ks*32+(lane>>4)*8+j)*256 + (g*64+ns*16+(lane&15))] )
__global__ void make_w3frag(const float* __restrict__ W3, bf16_t* __restrict__ W3f) {
    int t = blockIdx.x * blockDim.x + threadIdx.x;   // 0..65535
    int j = t & 7;
    int f = t >> 3;
    int lane = f & 63;
    int ns = (f >> 6) & 3;
    int ks = (f >> 8) & 7;
    int g = f >> 11;
    int k = ks * 32 + ((lane >> 4) << 3) + j;
    int n = g * 64 + ns * 16 + (lane & 15);
    W3f[t] = f2bf(W3[k * 256 + n]);
}

#define BIN_CHUNK 8192
#define NBMAX 392

// Bucket-level histogram: LDS-aggregated, <=NB global atomics per block.
__global__ __launch_bounds__(256)
void bin_count(const int* __restrict__ er, int* __restrict__ bcnt, int E, int N,
               int NB) {
    __shared__ int cnt[NBMAX];
    int tid = threadIdx.x;
    for (int b = tid; b < NB; b += 256) cnt[b] = 0;
    __syncthreads();
    int e0 = blockIdx.x * BIN_CHUNK;
    int n = min(BIN_CHUNK, E - e0);
    for (int i = tid; i < n; i += 256) {
        unsigned r = (unsigned)er[e0 + i];
        if (r < (unsigned)N) atomicAdd(&cnt[r >> 8], 1);
    }
    __syncthreads();
    for (int b = tid; b < NB; b += 256) {
        int c = cnt[b];
        if (c) atomicAdd(&bcnt[b], c);
    }
}

// Exclusive scan over NB (<512) bucket counts -> bucket_base[NB+1], bcur copy.
__global__ __launch_bounds__(512)
void scan_buckets(const int* __restrict__ bcnt, int* __restrict__ bucket_base,
                  int* __restrict__ bcur, int NB) {
    __shared__ int s[512];
    int t = threadIdx.x;
    int v = (t < NB) ? bcnt[t] : 0;
    s[t] = v;
    __syncthreads();
    for (int off = 1; off < 512; off <<= 1) {
        int u = (t >= off) ? s[t - off] : 0;
        __syncthreads();
        s[t] += u;
        __syncthreads();
    }
    if (t < NB) {
        int excl = s[t] - v;
        bucket_base[t] = excl;
        bcur[t] = excl;
        if (t == NB - 1) bucket_base[NB] = s[t];
    }
}

// Pass 1: bin edges into 256-row buckets. Packed entry: .x = r_local<<17 | c
// (c < 2^17), .y = float bits of val.
__global__ __launch_bounds__(256)
void bin_edges(const int* __restrict__ er, const int* __restrict__ ec,
               const float* __restrict__ ev, int* __restrict__ bcur,
               int2* __restrict__ binned, int E, int N, int NB) {
    __shared__ int cnt[NBMAX];
    __shared__ int resv[NBMAX];
    int tid = threadIdx.x;
    int e0 = blockIdx.x * BIN_CHUNK;
    int n = min(BIN_CHUNK, E - e0);
    for (int b = tid; b < NB; b += 256) cnt[b] = 0;
    __syncthreads();
    for (int i = tid; i < n; i += 256) {
        unsigned r = (unsigned)er[e0 + i];
        if (r < (unsigned)N) atomicAdd(&cnt[r >> 8], 1);
    }
    __syncthreads();
    for (int b = tid; b < NB; b += 256) {
        int c = cnt[b];
        resv[b] = c ? atomicAdd(&bcur[b], c) : 0;
        cnt[b] = 0;  // reuse as local cursor
    }
    __syncthreads();
    for (int i = tid; i < n; i += 256) {
        unsigned r = (unsigned)er[e0 + i];
        if (r < (unsigned)N) {
            unsigned c = (unsigned)ec[e0 + i];
            float v = ev[e0 + i];
            if (c >= (unsigned)N) { c = 0; v = 0.f; }  // sanitize, keep slot
            int b = (int)(r >> 8);
            int p = resv[b] + atomicAdd(&cnt[b], 1);
            binned[p] = make_int2((int)(((r & 255u) << 17) | c), __float_as_int(v));
        }
    }
}

// Pass 2: sort one bucket into CSR order with within-row ASCENDING COLUMNS:
// pass A counting-sorts by column band (c>>9) into LDS; pass B scatters by
// row back to global (arrival order preserves the c-ordering approximately).
// Emits row_ptr from the row scan. Fallback: row-only sort if n > BCAP.
#define BCAP 9216
__global__ __launch_bounds__(256)
void bucket_sort(const int* __restrict__ bucket_base, int2* __restrict__ csr,
                 int* __restrict__ row_ptr, int N, int NB) {
    __shared__ int2 ent[BCAP];
    __shared__ int h1[256], c1[256], h2[256], c2[256];
    int b = blockIdx.x;
    int tid = threadIdx.x;
    int r0 = b << 8;
    int e0 = bucket_base[b];
    int e1 = bucket_base[b + 1];
    int n = e1 - e0;
    h1[tid] = 0; h2[tid] = 0;
    __syncthreads();
    for (int i = tid; i < n; i += 256) {
        int2 p = csr[e0 + i];
        atomicAdd(&h1[(p.x & 0x1FFFF) >> 9], 1);
        atomicAdd(&h2[((unsigned)p.x >> 17) & 255u], 1);
    }
    __syncthreads();
    int v1 = h1[tid], v2 = h2[tid];
    for (int off = 1; off < 256; off <<= 1) {
        int u1 = (tid >= off) ? h1[tid - off] : 0;
        int u2 = (tid >= off) ? h2[tid - off] : 0;
        __syncthreads();
        h1[tid] += u1; h2[tid] += u2;
        __syncthreads();
    }
    c1[tid] = h1[tid] - v1;          // exclusive base, col-band key
    int base2 = h2[tid] - v2;        // exclusive base, row key
    c2[tid] = base2;
    if (r0 + tid < N) row_ptr[r0 + tid] = e0 + base2;
    if (b == NB - 1 && tid == 255) row_ptr[N] = e1;
    __syncthreads();
    if (n <= BCAP) {
        // pass A: re-read csr, scatter into ent ordered by column band
        for (int i = tid; i < n; i += 256) {
            int2 p = csr[e0 + i];
            int d = atomicAdd(&c1[(p.x & 0x1FFFF) >> 9], 1);
            ent[d] = p;
        }
        __syncthreads();
        // pass B: sequential read of c-ordered ent, scatter by row to global
        for (int i = tid; i < n; i += 256) {
            int2 p = ent[i];
            int d = atomicAdd(&c2[((unsigned)p.x >> 17) & 255u], 1);
            csr[e0 + d] = make_int2(p.x & 0x1FFFF, p.y);
        }
    } else {
        // fallback (statistically unreachable): row-only sort via staging
        for (int i = tid; i < n; i += 256) {
            if (i < BCAP) ent[i] = csr[e0 + i];
        }
        __syncthreads();
        for (int i = tid; i < n; i += 256) {
            int2 p = (i < BCAP) ? ent[i] : csr[e0 + i];
            int d = atomicAdd(&c2[((unsigned)p.x >> 17) & 255u], 1);
            csr[e0 + d] = make_int2(p.x & 0x1FFFF, p.y);
        }
    }
}

__device__ __forceinline__ void fma8(float* acc, float v, u16x8 hv) {
    #pragma unroll
    for (int k = 0; k < 8; ++k)
        acc[k] = fmaf(v, bf2f((bf16_t)hv[k]), acc[k]);
}

// Fused hop (R13 structure): block (256 thr, 4 waves) owns 32 rows, 16KB LDS.
//   Phase 1: wave w handles rows w*8..w*8+7 as 2 groups of 4, ROUND-ROBIN one
//     8-edge batch per row (rows sweep ascending columns in tandem with all
//     other resident rows -> h lines fetched once per generation; 4x gathers
//     in flight). Results -> XOR-swizzled s_tile.
//   Phase 2: barrier-free GEMM, wave w = column group w, B coalesced from
//     fragment-ordered W3f. One __syncthreads total.
__global__ __launch_bounds__(256, 5)
void fused_hop(const int* __restrict__ row_ptr, const int2* __restrict__ csr,
               const bf16_t* __restrict__ hin, const bf16_t* __restrict__ x0,
               const float* __restrict__ A2, const bf16_t* __restrict__ W3f,
               const float* __restrict__ bias, bf16_t* __restrict__ hout, int M) {
    __shared__ bf16_t s_tile[32 * 256];    // 16 KB, row stride 512 B, swizzled
    const int tid = threadIdx.x;
    const int w = tid >> 6, lane = tid & 63;
    const int bm = blockIdx.x * 32;
    const int half = lane >> 5, l32 = lane & 31, fo = l32 << 3;

    // ---- phase 1: spmm, 2 groups of 4 interleaved rows ----
    #pragma unroll
    for (int gq = 0; gq < 2; ++gq) {
        const int rbase = w * 8 + gq * 4;
        float acc[4][8];
        int e[4], e1v[4];
        #pragma unroll
        for (int r = 0; r < 4; ++r) {
            #pragma unroll
            for (int k = 0; k < 8; ++k) acc[r][k] = 0.f;
            int row = bm + rbase + r;
            if (row < M) {
                e[r] = row_ptr[row];
                e1v[r] = row_ptr[row + 1];
                if (half == 0) {
                    float a2 = A2[row];
                    u16x8 xv = *(const u16x8*)&x0[(row << 8) + fo];
                    #pragma unroll
                    for (int k = 0; k < 8; ++k) acc[r][k] = a2 * bf2f((bf16_t)xv[k]);
                }
            } else { e[r] = 0; e1v[r] = 0; }
        }
        // round-robin 8-edge batches: rows sweep columns in tandem
        bool more = true;
        while (more) {
            more = false;
            #pragma unroll
            for (int r = 0; r < 4; ++r) {
                if (e[r] + 8 <= e1v[r]) {
                    more = true;
                    int eb = e[r] + half;
                    int2 p0 = csr[eb], p1 = csr[eb + 2];
                    int2 p2 = csr[eb + 4], p3 = csr[eb + 6];
                    u16x8 h0 = *(const u16x8*)&hin[(p0.x << 8) + fo];
                    u16x8 h1 = *(const u16x8*)&hin[(p1.x << 8) + fo];
                    u16x8 h2 = *(const u16x8*)&hin[(p2.x << 8) + fo];
                    u16x8 h3 = *(const u16x8*)&hin[(p3.x << 8) + fo];
                    fma8(acc[r], __int_as_float(p0.y), h0);
                    fma8(acc[r], __int_as_float(p1.y), h1);
                    fma8(acc[r], __int_as_float(p2.y), h2);
                    fma8(acc[r], __int_as_float(p3.y), h3);
                    e[r] += 8;
                }
            }
        }
        // tails + reduce + LDS write
        #pragma unroll
        for (int r = 0; r < 4; ++r) {
            for (; e[r] + 2 <= e1v[r]; e[r] += 2) {
                int2 p = csr[e[r] + half];
                u16x8 hv = *(const u16x8*)&hin[(p.x << 8) + fo];
                fma8(acc[r], __int_as_float(p.y), hv);
            }
            if (e[r] < e1v[r] && half == 0) {
                int2 p = csr[e[r]];
                u16x8 hv = *(const u16x8*)&hin[(p.x << 8) + fo];
                fma8(acc[r], __int_as_float(p.y), hv);
            }
            #pragma unroll
            for (int k = 0; k < 8; ++k) acc[r][k] += __shfl_xor(acc[r][k], 32, 64);
            if (half == 0) {
                u16x8 o;
                #pragma unroll
                for (int k = 0; k < 8; ++k) o[k] = f2bf(acc[r][k]);
                int lrow = rbase + r;
                *(u16x8*)((char*)s_tile + lrow * 512 +
                          ((fo << 1) ^ ((lrow & 7) << 4))) = o;
            }
        }
    }
    __syncthreads();  // the ONLY block-wide barrier

    // ---- phase 2: GEMM relu(s + s@W3 + b3), wave w = col group w, no barriers ----
    const int q = lane >> 4, l16 = lane & 15;
    const int wn = w * 64;
    const bf16x8* bf = (const bf16x8*)W3f + ((size_t)w << 11);  // g*2048 frags
    f32x4 acc2[2][4] = {};
    #pragma unroll
    for (int ks = 0; ks < 8; ++ks) {
        bf16x8 afr[2], bfr[4];
        #pragma unroll
        for (int ns = 0; ns < 4; ++ns)
            bfr[ns] = bf[(ks * 4 + ns) * 64 + lane];   // coalesced: base + 16*lane
        #pragma unroll
        for (int ms = 0; ms < 2; ++ms) {
            int ar = ms * 16 + l16;
            afr[ms] = *(const bf16x8*)((const char*)s_tile + ar * 512 +
                       ((((ks << 5) + q * 8) << 1) ^ ((ar & 7) << 4)));
        }
        #pragma unroll
        for (int ms = 0; ms < 2; ++ms)
            #pragma unroll
            for (int ns = 0; ns < 4; ++ns)
                acc2[ms][ns] = __builtin_amdgcn_mfma_f32_16x16x32_bf16(
                    afr[ms], bfr[ns], acc2[ms][ns], 0, 0, 0);
    }

    // ---- epilogue: skip from LDS, bias, relu ----
    #pragma unroll
    for (int ms = 0; ms < 2; ++ms) {
        #pragma unroll
        for (int r = 0; r < 4; ++r) {
            int lrow = ms * 16 + q * 4 + r;
            int grow = bm + lrow;
            if (grow < M) {
                #pragma unroll
                for (int ns = 0; ns < 4; ++ns) {
                    int col = wn + ns * 16 + l16;
                    float v = acc2[ms][ns][r] + bias[col];
                    v += bf2f(*(const bf16_t*)((const char*)s_tile + lrow * 512 +
                              ((col << 1) ^ ((lrow & 7) << 4))));
                    v = fmaxf(v, 0.f);
                    hout[(size_t)grow * 256 + col] = f2bf(v);
                }
            }
        }
    }
}

// MFMA GEMM: C[M,Nfull] = epi(A[M,K] @ Bt[Nfull,K]^T). 4 waves, wave 64x64.
template <int WM, int WN, bool AF32, bool RELU, typename CT>
__global__ __launch_bounds__(256)
void mfma_gemm(const void* __restrict__ Av, const bf16_t* __restrict__ Bt,
               const float* __restrict__ bias, CT* __restrict__ C,
               int M, int K, int Nfull) {
    constexpr int TM = WM * 64;
    constexpr int TN = WN * 64;
    __shared__ bf16_t As[TM * 32];
    __shared__ bf16_t Bs[TN * 32];
    const int tid = threadIdx.x;
    const int w = tid >> 6, lane = tid & 63;
    const int q = lane >> 4, l16 = lane & 15;
    const int bm = blockIdx.x * TM;
    const int bn = blockIdx.y * TN;
    const int wm = (w % WM) * 64;
    const int wn = (w / WM) * 64;

    f32x4 acc[4][4] = {};

    for (int k0 = 0; k0 < K; k0 += 32) {
        // ---- stage A tile [TM][32] ----
        if constexpr (AF32) {
            constexpr int TPR = 256 / TM;      // threads per row
            constexpr int EPT = TM / 8;        // fp32 elems per thread
            const float* A = (const float*)Av;
            int row = tid / TPR;
            int gr = min(bm + row, M - 1);
            int off = (tid % TPR) * EPT;
            const float* src = A + (size_t)gr * K + k0 + off;
            bf16_t* dst = As + row * 32 + off;
            #pragma unroll
            for (int g = 0; g < EPT / 4; ++g) {
                float4 v = *(const float4*)(src + 4 * g);
                ushort4 u;
                u.x = f2bf(v.x); u.y = f2bf(v.y); u.z = f2bf(v.z); u.w = f2bf(v.w);
                *(ushort4*)(dst + 4 * g) = u;
            }
        } else {
            const bf16_t* A = (const bf16_t*)Av;
            #pragma unroll
            for (int r = 0; r < TM / 64; ++r) {
                int rowbase = r * 64 + w * 16;           // wave-uniform
                int row = rowbase + (lane >> 2);
                int gr = min(bm + row, M - 1);           // clamp tail rows
                const bf16_t* gp = A + (size_t)gr * K + k0 + (lane & 3) * 8;
                bf16_t* lp = As + rowbase * 32 + lane * 8;
                __builtin_amdgcn_global_load_lds(
                    (const __attribute__((address_space(1))) unsigned int*)gp,
                    (__attribute__((address_space(3))) unsigned int*)lp, 16, 0, 0);
            }
        }
        // ---- stage B tile [TN][32] from Bt (NxK row-major) ----
        #pragma unroll
        for (int r = 0; r < TN / 64; ++r) {
            int rowbase = r * 64 + w * 16;
            int row = rowbase + (lane >> 2);
            const bf16_t* gp = Bt + (size_t)(bn + row) * K + k0 + (lane & 3) * 8;
            bf16_t* lp = Bs + rowbase * 32 + lane * 8;
            __builtin_amdgcn_global_load_lds(
                (const __attribute__((address_space(1))) unsigned int*)gp,
                (__attribute__((address_space(3))) unsigned int*)lp, 16, 0, 0);
        }
        __syncthreads();

        bf16x8 afr[4], bfr[4];
        #pragma unroll
        for (int ms = 0; ms < 4; ++ms)
            afr[ms] = *(const bf16x8*)&As[(wm + ms * 16 + l16) * 32 + q * 8];
        #pragma unroll
        for (int ns = 0; ns < 4; ++ns)
            bfr[ns] = *(const bf16x8*)&Bs[(wn + ns * 16 + l16) * 32 + q * 8];
        #pragma unroll
        for (int ms = 0; ms < 4; ++ms)
            #pragma unroll
            for (int ns = 0; ns < 4; ++ns)
                acc[ms][ns] = __builtin_amdgcn_mfma_f32_16x16x32_bf16(
                    afr[ms], bfr[ns], acc[ms][ns], 0, 0, 0);
        __syncthreads();
    }

    // ---- epilogue ----
    #pragma unroll
    for (int ms = 0; ms < 4; ++ms) {
        #pragma unroll
        for (int r = 0; r < 4; ++r) {
            int row = bm + wm + ms * 16 + q * 4 + r;
            if (row < M) {
                #pragma unroll
                for (int ns = 0; ns < 4; ++ns) {
                    int col = bn + wn + ns * 16 + l16;
                    float v = acc[ms][ns][r] + bias[col];
                    if constexpr (RELU) v = fmaxf(v, 0.f);
                    if constexpr (sizeof(CT) == 2) C[(size_t)row * Nfull + col] = (CT)f2bf(v);
                    else                           C[(size_t)row * Nfull + col] = (CT)v;
                }
            }
        }
    }
}

extern "C" void kernel_launch(void* const* d_in, const int* in_sizes, int n_in,
                              void* d_out, int out_size, void* d_ws, size_t ws_size,
                              hipStream_t stream) {
    const float* x   = (const float*)d_in[0];
    const int* erow  = (const int*)d_in[1];
    const int* ecol  = (const int*)d_in[2];
    const float* ev  = (const float*)d_in[3];
    const float* A2  = (const float*)d_in[4];
    const float* W1  = (const float*)d_in[5];
    const float* b1  = (const float*)d_in[6];
    const float* W3  = (const float*)d_in[7];
    const float* b3  = (const float*)d_in[8];
    const float* W2  = (const float*)d_in[9];
    const float* b2  = (const float*)d_in[10];
    float* out = (float*)d_out;

    const int N   = in_sizes[4];        // 100000 nodes
    const int E   = in_sizes[1];        // 3200000 edges
    const int NIN = in_sizes[0] / N;    // 512
    const int NH  = in_sizes[6];        // 256
    const int NO  = in_sizes[10];       // 64
    if (NH != 256 || NIN != 512 || NO != 64) return;  // layout hard-coded
    const int NB = (N + 255) >> 8;      // 391 buckets
    if (NB > NBMAX) return;

    char* ws = (char*)d_ws;
    size_t off = 0;
    auto alloc = [&](size_t bytes) -> void* {
        void* p = ws + off;
        off += (bytes + 255) & ~(size_t)255;
        return p;
    };
    bf16_t* x0     = (bf16_t*)alloc((size_t)N * NH * 2);
    bf16_t* hA     = (bf16_t*)alloc((size_t)N * NH * 2);
    bf16_t* hB     = (bf16_t*)alloc((size_t)N * NH * 2);
    int*   row_ptr = (int*)alloc((size_t)(N + 1) * 4);
    int*   bcnt    = (int*)alloc((size_t)NB * 4);
    int*   bbase   = (int*)alloc((size_t)(NB + 1) * 4);
    int*   bcur    = (int*)alloc((size_t)NB * 4);
    int2*  csr     = (int2*)alloc((size_t)E * 8);
    bf16_t* W1t    = (bf16_t*)alloc((size_t)NIN * NH * 2);  // [256][512]
    bf16_t* W3f    = (bf16_t*)alloc((size_t)NH * NH * 2);   // fragment-ordered
    bf16_t* W2t    = (bf16_t*)alloc((size_t)NH * NO * 2);   // [64][256]
    if (off > ws_size) return;  // visible absmax failure, not an OOB crash

    // --- build CSR (two-pass bucketed, bucket-level counting) ---
    zero_i32<<<1, 512, 0, stream>>>(bcnt, NB);
    bin_count<<<(E + BIN_CHUNK - 1) / BIN_CHUNK, 256, 0, stream>>>(
        erow, bcnt, E, N, NB);
    scan_buckets<<<1, 512, 0, stream>>>(bcnt, bbase, bcur, NB);
    bin_edges<<<(E + BIN_CHUNK - 1) / BIN_CHUNK, 256, 0, stream>>>(
        erow, ecol, ev, bcur, csr, E, N, NB);
    bucket_sort<<<NB, 256, 0, stream>>>(bbase, csr, row_ptr, N, NB);
    transpose_w<<<(NIN * NH + 255) / 256, 256, 0, stream>>>(W1, W1t, NIN, NH);
    make_w3frag<<<(NH * NH + 255) / 256, 256, 0, stream>>>(W3, W3f);
    transpose_w<<<(NH * NO + 255) / 256, 256, 0, stream>>>(W2, W2t, NH, NO);

    // --- x0 = relu(x @ W1 + b1): fp32 A, 64x256 tile (A read once) ---
    dim3 g1((N + 63) / 64, 1);
    mfma_gemm<1, 4, true, true, bf16_t><<<g1, 256, 0, stream>>>(
        x, W1t, b1, x0, N, NIN, NH);

    // --- 10 fused hops ---
    const bf16_t* hin = x0;
    bf16_t* hout = hA;
    for (int hop = 0; hop < 10; ++hop) {
        fused_hop<<<(N + 31) / 32, 256, 0, stream>>>(
            row_ptr, csr, hin, x0, A2, W3f, b3, hout, N);
        hin = hout;
        hout = (hout == hA) ? hB : hA;
    }

    // --- out = h @ W2 + b2: 256x64 tile (N=64) ---
    dim3 g2((N + 255) / 256, 1);
    mfma_gemm<4, 1, false, false, float><<<g2, 256, 0, stream>>>(
        (const void*)hin, W2t, b2, out, N, NH, NO);
}